// Round 3
// baseline (236.941 us; speedup 1.0000x reference)
//
#include <hip/hip_runtime.h>
#include <math.h>

#define D_EMB 512
#define HD 64
#define BB 8
#define NN 2048
#define MROWS (BB*NN)   // 16384

typedef short short8  __attribute__((ext_vector_type(8)));
typedef short short4v __attribute__((ext_vector_type(4)));
typedef float f32x4   __attribute__((ext_vector_type(4)));

__device__ __forceinline__ short f2bf(float x){
    unsigned u = __float_as_uint(x);
    unsigned r = (u + 0x7fffu + ((u >> 16) & 1u)) >> 16;
    return (short)r;
}
__device__ __forceinline__ float bf2f(short b){
    return __uint_as_float(((unsigned)(unsigned short)b) << 16);
}

// ---------------- Wt[n][k] (bf16) <- W[k][n] (f32)
__global__ __launch_bounds__(256)
void wt_kernel(const float* __restrict__ W, short* __restrict__ Wt){
    for (int idx = blockIdx.x * 256 + threadIdx.x; idx < D_EMB*HD; idx += 8*256){
        int k = idx >> 6, n = idx & 63;
        Wt[n*D_EMB + k] = f2bf(W[idx]);
    }
}

// ---------------- Projection. 16 rows per wave, MFMA. Q,K row-major bf16;
// V written TRANSPOSED per batch: Vt[b][d][n] so attention PV B-frags are
// contiguous 16B global loads (no LDS transpose, no barriers in attention).
__global__ __launch_bounds__(256)
void proj_kernel(const float* __restrict__ Xq, const float* __restrict__ Xk,
                 const float* __restrict__ Xv, const short* __restrict__ Wt,
                 short* __restrict__ Qb, short* __restrict__ Kb,
                 short* __restrict__ Vt)
{
    const int lane = threadIdx.x & 63;
    const int lc = lane & 15, quad = lane >> 4;
    const int wid = blockIdx.x * 4 + (threadIdx.x >> 6);
    const int m0 = wid * 16;                 // 3072 waves * 16 rows = 49152
    const int tensor = m0 >> 14;             // 0=Q 1=K 2=V
    const int rloc = m0 & (MROWS - 1);
    const float* X = (tensor == 0) ? Xq : (tensor == 1 ? Xk : Xv);

    f32x4 acc[4];
#pragma unroll
    for (int t = 0; t < 4; ++t)
#pragma unroll
        for (int r = 0; r < 4; ++r) acc[t][r] = 0.f;

    for (int c16 = 0; c16 < 16; ++c16){
        const int k0 = c16 * 32;
        const float* xr = X + (size_t)(rloc + lc) * D_EMB + k0 + quad*8;
        float4 f0 = *(const float4*)xr;
        float4 f1 = *(const float4*)(xr + 4);
        short8 a;
        a[0]=f2bf(f0.x); a[1]=f2bf(f0.y); a[2]=f2bf(f0.z); a[3]=f2bf(f0.w);
        a[4]=f2bf(f1.x); a[5]=f2bf(f1.y); a[6]=f2bf(f1.z); a[7]=f2bf(f1.w);
#pragma unroll
        for (int t = 0; t < 4; ++t){
            short8 bf = *(const short8*)(Wt + (size_t)(t*16 + lc)*D_EMB + k0 + quad*8);
            acc[t] = __builtin_amdgcn_mfma_f32_16x16x32_bf16(a, bf, acc[t], 0,0,0);
        }
    }
    // D layout: col = lane&15 (via t*16+lc), row = quad*4 + r
    if (tensor < 2){
        short* outp = (tensor == 0) ? Qb : Kb;
#pragma unroll
        for (int t = 0; t < 4; ++t)
#pragma unroll
            for (int r = 0; r < 4; ++r)
                outp[(size_t)(rloc + quad*4 + r)*HD + t*16 + lc] = f2bf(acc[t][r]);
    } else {
        const int bb = rloc >> 11;               // batch
        const int n0 = (rloc & 2047) + quad*4;   // seq pos base (8B aligned)
#pragma unroll
        for (int t = 0; t < 4; ++t){
            short4v p;
            p[0]=f2bf(acc[t][0]); p[1]=f2bf(acc[t][1]);
            p[2]=f2bf(acc[t][2]); p[3]=f2bf(acc[t][3]);
            *(short4v*)(Vt + ((size_t)(bb*HD + t*16 + lc))*NN + n0) = p;
        }
    }
}

// ---------------- Attention partials: barrier-free flash, split-K.
// Wave-unit = (b, 16-row strip s, k-chunk c). 2560 units, 640 blocks.
// nchunks(s) = 1 + s/32.  s<32 (C==1) writes out directly.
template<bool FP32P>
__global__ __launch_bounds__(256)
void attn_part(const short* __restrict__ Qb, const short* __restrict__ Kb,
               const short* __restrict__ Vt, const unsigned char* __restrict__ pad,
               const int* __restrict__ mflag, float* __restrict__ out,
               float* __restrict__ Mp, float* __restrict__ Lp, void* __restrict__ Op)
{
    __shared__ short sP[4][16][72];   // wave-private; stride 72 keeps b128 reads 16B-aligned
    const int tid = threadIdx.x, lane = tid & 63, lc = lane & 15, quad = lane >> 4, w = tid >> 6;
    const int unit = blockIdx.x * 4 + w;
    const int b = unit / 320;
    const int rem = unit - b * 320;
    int s, c;
    if (rem < 32)      { s = rem;                     c = 0; }
    else if (rem < 96) { s = 32 + ((rem - 32) >> 1);  c = (rem - 32) & 1; }
    else if (rem < 192){ s = 64 + (rem - 96) / 3;     c = (rem - 96) % 3; }
    else               { s = 96 + ((rem - 192) >> 2); c = (rem - 192) & 3; }

    const bool causal = (mflag[0] != 0);
    const int q0 = s * 16;
    const int ntc = (q0 + 79) >> 6;            // tiles needed under causal
    const int T = causal ? ntc : (NN / 64);
    const int C = 1 + (s >> 5);
    const int qq = (T + C - 1) / C;
    const int t0 = c * qq;
    const int t1 = min(t0 + qq, T);

    const float scale = 0.04419417382415922f;  // 1/sqrt(512)
    const unsigned char* padb = pad + (size_t)b * NN;

    const short* qrow = Qb + ((size_t)b * NN + q0 + lc) * HD;
    short8 qf0 = *(const short8*)(qrow + quad * 8);
    short8 qf1 = *(const short8*)(qrow + 32 + quad * 8);

    f32x4 o[4]; float m_i[4], l_i[4];
#pragma unroll
    for (int t = 0; t < 4; ++t)
#pragma unroll
        for (int r = 0; r < 4; ++r) o[t][r] = 0.f;
#pragma unroll
    for (int r = 0; r < 4; ++r){ m_i[r] = -INFINITY; l_i[r] = 0.f; }

    for (int kt = t0; kt < t1; ++kt){
        const int k0 = kt * 64;
        f32x4 sc[4];
#pragma unroll
        for (int t = 0; t < 4; ++t)
#pragma unroll
            for (int r = 0; r < 4; ++r) sc[t][r] = 0.f;
#pragma unroll
        for (int t = 0; t < 4; ++t){
            const short* kr = Kb + ((size_t)b*NN + k0 + t*16 + lc)*HD;
            short8 kf0 = *(const short8*)(kr + quad*8);
            short8 kf1 = *(const short8*)(kr + 32 + quad*8);
            sc[t] = __builtin_amdgcn_mfma_f32_16x16x32_bf16(qf0, kf0, sc[t], 0,0,0);
            sc[t] = __builtin_amdgcn_mfma_f32_16x16x32_bf16(qf1, kf1, sc[t], 0,0,0);
        }
        const bool diag = causal && (kt == ntc - 1);
#pragma unroll
        for (int t = 0; t < 4; ++t){
            const int kg = k0 + t*16 + lc;
            const bool pb = padb[kg];
#pragma unroll
            for (int r = 0; r < 4; ++r){
                float v = sc[t][r] * scale;
                if (pb) v = -INFINITY;
                if (diag && kg > q0 + quad*4 + r) v = -INFINITY;
                sc[t][r] = v;
            }
        }
        float alpha[4];
#pragma unroll
        for (int r = 0; r < 4; ++r){
            float tm = fmaxf(fmaxf(sc[0][r], sc[1][r]), fmaxf(sc[2][r], sc[3][r]));
            tm = fmaxf(tm, __shfl_xor(tm, 1));
            tm = fmaxf(tm, __shfl_xor(tm, 2));
            tm = fmaxf(tm, __shfl_xor(tm, 4));
            tm = fmaxf(tm, __shfl_xor(tm, 8));
            float mn = fmaxf(m_i[r], tm);
            alpha[r] = __expf(m_i[r] - mn);
            m_i[r] = mn;
        }
#pragma unroll
        for (int r = 0; r < 4; ++r){
            float ps = 0.f;
#pragma unroll
            for (int t = 0; t < 4; ++t){
                float p = __expf(sc[t][r] - m_i[r]);
                ps += p;
                sP[w][quad*4 + r][t*16 + lc] = f2bf(p);
            }
            ps += __shfl_xor(ps, 1); ps += __shfl_xor(ps, 2);
            ps += __shfl_xor(ps, 4); ps += __shfl_xor(ps, 8);
            l_i[r] = l_i[r]*alpha[r] + ps;
#pragma unroll
            for (int t = 0; t < 4; ++t) o[t][r] *= alpha[r];
        }
        short8 pf0 = *(const short8*)&sP[w][lc][quad*8];
        short8 pf1 = *(const short8*)&sP[w][lc][32 + quad*8];
#pragma unroll
        for (int t = 0; t < 4; ++t){
            const short* vr = Vt + ((size_t)b*HD + t*16 + lc)*NN + k0;
            short8 vf0 = *(const short8*)(vr + quad*8);
            short8 vf1 = *(const short8*)(vr + 32 + quad*8);
            o[t] = __builtin_amdgcn_mfma_f32_16x16x32_bf16(pf0, vf0, o[t], 0,0,0);
            o[t] = __builtin_amdgcn_mfma_f32_16x16x32_bf16(pf1, vf1, o[t], 0,0,0);
        }
    }

    if (C == 1){
#pragma unroll
        for (int r = 0; r < 4; ++r){
            float inv = 1.f / l_i[r];
            float* orow = out + ((size_t)b*NN + q0 + quad*4 + r)*HD;
#pragma unroll
            for (int t = 0; t < 4; ++t) orow[t*16 + lc] = o[t][r] * inv;
        }
    } else {
        const int base2 = (s < 64) ? 2*(s-32) : (s < 96 ? 64 + 3*(s-64) : 160 + 4*(s-96));
        const int pu = b*288 + base2 + c;
        if (FP32P){
            float* op = (float*)Op + (size_t)pu * 1024;
#pragma unroll
            for (int t = 0; t < 4; ++t)
#pragma unroll
                for (int r = 0; r < 4; ++r)
                    op[(quad*4 + r)*64 + t*16 + lc] = o[t][r];
        } else {
            short* op = (short*)Op + (size_t)pu * 1024;
#pragma unroll
            for (int t = 0; t < 4; ++t)
#pragma unroll
                for (int r = 0; r < 4; ++r)
                    op[(quad*4 + r)*64 + t*16 + lc] = f2bf(o[t][r]);
        }
        if (lc == 0){
#pragma unroll
            for (int r = 0; r < 4; ++r){
                Mp[pu*16 + quad*4 + r] = m_i[r];
                Lp[pu*16 + quad*4 + r] = l_i[r];
            }
        }
    }
}

// ---------------- Combine partials for strips s>=32. 768 wave-units.
template<bool FP32P>
__global__ __launch_bounds__(256)
void attn_combine(const float* __restrict__ Mp, const float* __restrict__ Lp,
                  const void* __restrict__ Op, float* __restrict__ out)
{
    const int tid = threadIdx.x, lane = tid & 63, w = tid >> 6;
    const int unit = blockIdx.x * 4 + w;
    const int b = unit / 96;
    const int s = 32 + (unit - b * 96);
    const int C = 1 + (s >> 5);
    const int base2 = (s < 64) ? 2*(s-32) : (s < 96 ? 64 + 3*(s-64) : 160 + 4*(s-96));
    const int pu0 = b*288 + base2;

    for (int row = 0; row < 16; ++row){
        float m = -INFINITY, mc[4];
        for (int c = 0; c < C; ++c){ mc[c] = Mp[(pu0+c)*16 + row]; m = fmaxf(m, mc[c]); }
        float l = 0.f, wg[4];
        for (int c = 0; c < C; ++c){
            wg[c] = __expf(mc[c] - m);
            l += Lp[(pu0+c)*16 + row] * wg[c];
        }
        float acc = 0.f;
        for (int c = 0; c < C; ++c){
            float ov;
            if (FP32P) ov = ((const float*)Op)[((size_t)(pu0+c)*16 + row)*64 + lane];
            else       ov = bf2f(((const short*)Op)[((size_t)(pu0+c)*16 + row)*64 + lane]);
            acc += ov * wg[c];
        }
        out[((size_t)b*NN + s*16 + row)*HD + lane] = acc / l;
    }
}

extern "C" void kernel_launch(void* const* d_in, const int* in_sizes, int n_in,
                              void* d_out, int out_size, void* d_ws, size_t ws_size,
                              hipStream_t stream) {
    const float* key_in   = (const float*)d_in[0];
    const float* query_in = (const float*)d_in[1];
    const float* value_in = (const float*)d_in[2];
    const unsigned char* pad = (const unsigned char*)d_in[3];
    const int* mflag      = (const int*)d_in[4];
    const float* Wk       = (const float*)d_in[5];
    // W_query / W_value unused — reference uses W_key for Q, K and V.

    short* Qb = (short*)d_ws;                    // 2 MiB
    short* Kb = Qb + (size_t)MROWS*HD;           // 2 MiB
    short* Vt = Kb + (size_t)MROWS*HD;           // 2 MiB, [b][d][n]
    short* Wt = Vt + (size_t)MROWS*HD;           // 64 KiB
    float* Mp = (float*)(Wt + D_EMB*HD);         // 2304*16 f32
    float* Lp = Mp + 2304*16;
    void*  Op = (void*)(Lp + 2304*16);           // 2304*1024 x (f32|bf16)

    // fp32 partials need 16,089,088 B total; bf16 needs 11,370,496 (proven fits).
    const bool fp32p = (ws_size >= (size_t)16200000);

    wt_kernel<<<8, 256, 0, stream>>>(Wk, Wt);
    proj_kernel<<<768, 256, 0, stream>>>(query_in, key_in, value_in, Wt, Qb, Kb, Vt);
    if (fp32p){
        attn_part<true><<<640, 256, 0, stream>>>(Qb, Kb, Vt, pad, mflag, (float*)d_out, Mp, Lp, Op);
        attn_combine<true><<<192, 256, 0, stream>>>(Mp, Lp, Op, (float*)d_out);
    } else {
        attn_part<false><<<640, 256, 0, stream>>>(Qb, Kb, Vt, pad, mflag, (float*)d_out, Mp, Lp, Op);
        attn_combine<false><<<192, 256, 0, stream>>>(Mp, Lp, Op, (float*)d_out);
    }
}

// Round 4
// 231.167 us; speedup vs baseline: 1.0250x; 1.0250x over previous
//
#include <hip/hip_runtime.h>
#include <hip/hip_bf16.h>
#include <math.h>

#define D_EMB 512
#define HD 64
#define BB 8
#define NN 2048
#define MROWS (BB*NN)   // 16384

typedef short short8  __attribute__((ext_vector_type(8)));
typedef short short4v __attribute__((ext_vector_type(4)));
typedef float f32x4   __attribute__((ext_vector_type(4)));

// scale(1/sqrt(512)) * log2(e): folded into Qb so P = exp2(S') directly
#define QSCALE 0.063758708f

__device__ __forceinline__ short f2bf(float x){
    unsigned u = __float_as_uint(x);
    unsigned r = (u + 0x7fffu + ((u >> 16) & 1u)) >> 16;
    return (short)r;
}
__device__ __forceinline__ float bf2f(short b){
    return __uint_as_float(((unsigned)(unsigned short)b) << 16);
}
__device__ __forceinline__ unsigned pkbf(float a, float b){
    __hip_bfloat162 h = __float22bfloat162_rn(make_float2(a, b));
    unsigned u; __builtin_memcpy(&u, &h, 4); return u;
}

// ---------------- Wt[n][k] (bf16) <- W[k][n] (f32)
__global__ __launch_bounds__(256)
void wt_kernel(const float* __restrict__ W, short* __restrict__ Wt){
    for (int idx = blockIdx.x * 256 + threadIdx.x; idx < D_EMB*HD; idx += 8*256){
        int k = idx >> 6, n = idx & 63;
        Wt[n*D_EMB + k] = f2bf(W[idx]);
    }
}

// ---------------- Projection. 16 rows/wave, MFMA. Q scaled by QSCALE.
// V written transposed: Vt[b][d][n].
__global__ __launch_bounds__(256)
void proj_kernel(const float* __restrict__ Xq, const float* __restrict__ Xk,
                 const float* __restrict__ Xv, const short* __restrict__ Wt,
                 short* __restrict__ Qb, short* __restrict__ Kb,
                 short* __restrict__ Vt)
{
    const int lane = threadIdx.x & 63;
    const int lc = lane & 15, quad = lane >> 4;
    const int wid = blockIdx.x * 4 + (threadIdx.x >> 6);
    const int m0 = wid * 16;
    const int tensor = m0 >> 14;             // 0=Q 1=K 2=V
    const int rloc = m0 & (MROWS - 1);
    const float* X = (tensor == 0) ? Xq : (tensor == 1 ? Xk : Xv);

    f32x4 acc[4];
#pragma unroll
    for (int t = 0; t < 4; ++t)
#pragma unroll
        for (int r = 0; r < 4; ++r) acc[t][r] = 0.f;

#pragma unroll 4
    for (int c16 = 0; c16 < 16; ++c16){
        const int k0 = c16 * 32;
        const float* xr = X + (size_t)(rloc + lc) * D_EMB + k0 + quad*8;
        float4 f0 = *(const float4*)xr;
        float4 f1 = *(const float4*)(xr + 4);
        union { short8 s8; unsigned u[4]; } a;
        a.u[0] = pkbf(f0.x, f0.y); a.u[1] = pkbf(f0.z, f0.w);
        a.u[2] = pkbf(f1.x, f1.y); a.u[3] = pkbf(f1.z, f1.w);
#pragma unroll
        for (int t = 0; t < 4; ++t){
            short8 bf = *(const short8*)(Wt + (size_t)(t*16 + lc)*D_EMB + k0 + quad*8);
            acc[t] = __builtin_amdgcn_mfma_f32_16x16x32_bf16(a.s8, bf, acc[t], 0,0,0);
        }
    }

    if (tensor == 0){
#pragma unroll
        for (int t = 0; t < 4; ++t)
#pragma unroll
            for (int r = 0; r < 4; ++r)
                Qb[(size_t)(rloc + quad*4 + r)*HD + t*16 + lc] = f2bf(acc[t][r] * QSCALE);
    } else if (tensor == 1){
#pragma unroll
        for (int t = 0; t < 4; ++t)
#pragma unroll
            for (int r = 0; r < 4; ++r)
                Kb[(size_t)(rloc + quad*4 + r)*HD + t*16 + lc] = f2bf(acc[t][r]);
    } else {
        const int bb = rloc >> 11;
        const int n0 = (rloc & 2047) + quad*4;
#pragma unroll
        for (int t = 0; t < 4; ++t){
            union { short4v s4; unsigned u[2]; } p;
            p.u[0] = pkbf(acc[t][0], acc[t][1]);
            p.u[1] = pkbf(acc[t][2], acc[t][3]);
            *(short4v*)(Vt + ((size_t)(bb*HD + t*16 + lc))*NN + n0) = p.s4;
        }
    }
}

// ---------------- Attention partials: barrier-free, max-free softmax, split-K.
// Computes S^T = K·Q^T (both operands contiguous row-major); P^T packed to LDS
// (b64), PV via A=P (sP rows), B=V (Vt rows). C = 1+(s>>CSH) chunks per strip.
template<int CSH>
__global__ __launch_bounds__(256)
void attn_part(const short* __restrict__ Qb, const short* __restrict__ Kb,
               const short* __restrict__ Vt, const unsigned char* __restrict__ pad,
               const int* __restrict__ mflag, float* __restrict__ out,
               float* __restrict__ Lp, short* __restrict__ Op)
{
    constexpr int G   = 1 << CSH;
    constexpr int NG  = 128 / G;
    constexpr int UPB = 64 * (NG + 1);            // wave-units per batch
    constexpr int PPB = G * (NG - 1) * (NG + 2) / 2;

    __shared__ short sP[4][16][80];               // [wave][q][n], stride 80 -> 16B-aligned b128
    const int tid = threadIdx.x, lane = tid & 63, lc = lane & 15, quad = lane >> 4, w = tid >> 6;
    const int unit = blockIdx.x * 4 + w;
    const int b = unit / UPB;
    int rem = unit - b * UPB;
    int g = 0, off = 0;
    while (rem >= off + G * (g + 1)) { off += G * (g + 1); ++g; }
    const int rr = rem - off;
    const int C = g + 1;
    const int s = G * g + rr / C;
    const int c = rr - (rr / C) * C;

    const bool causal = (mflag[0] != 0);
    const int q0 = s * 16;
    const int T = causal ? ((s >> 2) + 1) : (NN / 64);
    const int qq = (T + C - 1) / C;
    const int t0 = c * qq;
    const int t1 = min(t0 + qq, T);
    const unsigned char* padb = pad + (size_t)b * NN;

    // Q B-fragments (scaled at proj): B[k=d=quad*8+j][col=q=lc]
    const short* qrow = Qb + ((size_t)b * NN + q0 + lc) * HD;
    const short8 qf0 = *(const short8*)(qrow + quad * 8);
    const short8 qf1 = *(const short8*)(qrow + 32 + quad * 8);

    f32x4 o[4];
#pragma unroll
    for (int t = 0; t < 4; ++t)
#pragma unroll
        for (int r = 0; r < 4; ++r) o[t][r] = 0.f;
    float lacc = 0.f;

    for (int kt = t0; kt < t1; ++kt){
        const int k0 = kt * 64;
        // K A-frags + V B-frags up front (independent -> overlap MFMA/exp)
        short8 kf0[4], kf1[4], vf0[4], vf1[4];
#pragma unroll
        for (int t = 0; t < 4; ++t){
            const short* kr = Kb + ((size_t)b*NN + k0 + t*16 + lc)*HD;
            kf0[t] = *(const short8*)(kr + quad*8);
            kf1[t] = *(const short8*)(kr + 32 + quad*8);
            const short* vr = Vt + ((size_t)b*HD + t*16 + lc)*NN + k0;
            vf0[t] = *(const short8*)(vr + quad*8);
            vf1[t] = *(const short8*)(vr + 32 + quad*8);
        }
        // S^T[n][q]: D row = n = k0 + t*16 + quad*4 + r, col = q = q0 + lc
        f32x4 st[4];
#pragma unroll
        for (int t = 0; t < 4; ++t){
#pragma unroll
            for (int r = 0; r < 4; ++r) st[t][r] = 0.f;
            st[t] = __builtin_amdgcn_mfma_f32_16x16x32_bf16(kf0[t], qf0, st[t], 0,0,0);
            st[t] = __builtin_amdgcn_mfma_f32_16x16x32_bf16(kf1[t], qf1, st[t], 0,0,0);
        }
        const bool dg = causal && (kt == T - 1);
        const int thr = q0 + lc - k0;             // keep iff n_local <= thr
#pragma unroll
        for (int t = 0; t < 4; ++t){
            uchar4 pb = *(const uchar4*)(padb + k0 + t*16 + quad*4);
            float e[4];
#pragma unroll
            for (int r = 0; r < 4; ++r){
                float v = st[t][r];
                const unsigned char pr = (r==0)?pb.x:(r==1)?pb.y:(r==2)?pb.z:pb.w;
                const int nloc = t*16 + quad*4 + r;
                if (pr || (dg && nloc > thr)) v = -INFINITY;
                e[r] = exp2f(v);
                lacc += e[r];
            }
            union { short4v s4; unsigned u[2]; } pk;
            pk.u[0] = pkbf(e[0], e[1]);
            pk.u[1] = pkbf(e[2], e[3]);
            *(short4v*)&sP[w][lc][t*16 + quad*4] = pk.s4;
        }
        // PV: A = P (sP row lc), B = V (Vt rows)
        const short8 pf0 = *(const short8*)&sP[w][lc][quad*8];
        const short8 pf1 = *(const short8*)&sP[w][lc][32 + quad*8];
#pragma unroll
        for (int t = 0; t < 4; ++t){
            o[t] = __builtin_amdgcn_mfma_f32_16x16x32_bf16(pf0, vf0[t], o[t], 0,0,0);
            o[t] = __builtin_amdgcn_mfma_f32_16x16x32_bf16(pf1, vf1[t], o[t], 0,0,0);
        }
    }

    // reduce l across quads: lane(lc) pattern covers n = quad*4+{0..3} (mod 16)
    lacc += __shfl_xor(lacc, 16);
    lacc += __shfl_xor(lacc, 32);

    if (C == 1){
        float linv[4];
#pragma unroll
        for (int r = 0; r < 4; ++r) linv[r] = 1.f / __shfl(lacc, quad*4 + r);
#pragma unroll
        for (int r = 0; r < 4; ++r){
            float* orow = out + ((size_t)b*NN + q0 + quad*4 + r)*HD;
#pragma unroll
            for (int t = 0; t < 4; ++t) orow[t*16 + lc] = o[t][r] * linv[r];
        }
    } else {
        const int base = G*(g-1)*(g+2)/2 + (s - G*g)*(1+g);
        const int pu = b*PPB + base + c;
        short* op = Op + (size_t)pu * 1024;
#pragma unroll
        for (int t = 0; t < 4; ++t)
#pragma unroll
            for (int r = 0; r < 4; ++r)
                op[(quad*4 + r)*64 + t*16 + lc] = f2bf(o[t][r]);
        if (lane < 16) Lp[pu*16 + lane] = lacc;
    }
}

// ---------------- Combine: out = sum_c o_c / sum_c l_c  (max-free -> no weights)
template<int CSH>
__global__ __launch_bounds__(256)
void attn_combine(const float* __restrict__ Lp, const short* __restrict__ Op,
                  float* __restrict__ out)
{
    constexpr int G    = 1 << CSH;
    constexpr int NG   = 128 / G;
    constexpr int NSTR = 128 - G;
    constexpr int PPB  = G * (NG - 1) * (NG + 2) / 2;
    const int tid = threadIdx.x, lane = tid & 63, w = tid >> 6;
    const int unit = blockIdx.x * 4 + w;
    const int b = unit / NSTR;
    const int s = G + (unit - b * NSTR);
    const int g = s >> CSH;
    const int C = 1 + g;
    const int base = G*(g-1)*(g+2)/2 + (s - G*g)*(1+g);
    const int pu0 = b*PPB + base;

    for (int row = 0; row < 16; ++row){
        float l = 0.f, acc = 0.f;
        for (int c = 0; c < C; ++c){
            l   += Lp[(pu0 + c)*16 + row];
            acc += bf2f(Op[((size_t)(pu0 + c)*16 + row)*64 + lane]);
        }
        out[((size_t)b*NN + s*16 + row)*HD + lane] = acc / l;
    }
}

extern "C" void kernel_launch(void* const* d_in, const int* in_sizes, int n_in,
                              void* d_out, int out_size, void* d_ws, size_t ws_size,
                              hipStream_t stream) {
    const float* key_in   = (const float*)d_in[0];
    const float* query_in = (const float*)d_in[1];
    const float* value_in = (const float*)d_in[2];
    const unsigned char* pad = (const unsigned char*)d_in[3];
    const int* mflag      = (const int*)d_in[4];
    const float* Wk       = (const float*)d_in[5];
    // W_query / W_value unused — reference applies W_key to Q, K and V.

    short* Qb = (short*)d_ws;                    // 2 MiB (pre-scaled by QSCALE)
    short* Kb = Qb + (size_t)MROWS*HD;           // 2 MiB
    short* Vt = Kb + (size_t)MROWS*HD;           // 2 MiB, [b][d][n]
    short* Wt = Vt + (size_t)MROWS*HD;           // 64 KiB
    float* Lp = (float*)(Wt + D_EMB*HD);

    wt_kernel<<<8, 256, 0, stream>>>(Wk, Wt);
    proj_kernel<<<768, 256, 0, stream>>>(query_in, key_in, value_in, Wt, Qb, Kb, Vt);

    if (ws_size >= (size_t)15818752){
        // CSH=4: 4608 wave-units, <=4-tile critical path; partials 8*560
        short* Op = (short*)(Lp + 8*560*16);
        attn_part<4><<<1152, 256, 0, stream>>>(Qb, Kb, Vt, pad, mflag, (float*)d_out, Lp, Op);
        attn_combine<4><<<224, 256, 0, stream>>>(Lp, Op, (float*)d_out);
    } else {
        // CSH=5: proven-fit fallback (11.2 MB total), 2560 wave-units
        short* Op = (short*)(Lp + 8*288*16);
        attn_part<5><<<640, 256, 0, stream>>>(Qb, Kb, Vt, pad, mflag, (float*)d_out, Lp, Op);
        attn_combine<5><<<192, 256, 0, stream>>>(Lp, Op, (float*)d_out);
    }
}